// Round 21
// baseline (233.988 us; speedup 1.0000x reference)
//
#include <hip/hip_runtime.h>
#include <hip/hip_bf16.h>

// ---------- types / helpers ----------
typedef __attribute__((ext_vector_type(4))) float f32x4;   // MFMA C/D frag
typedef __attribute__((ext_vector_type(4))) int   int4v;   // one 16B load
typedef __attribute__((ext_vector_type(8))) int   int8v;   // K=128 fp8 A/B frag (32B)

// float -> OCP e4m3fn byte (cold path: weight prep only)
__device__ __forceinline__ unsigned char f2fp8(float f) {
    unsigned char s = (__float_as_uint(f) >> 24) & 0x80;
    float a = fabsf(f);
    if (a >= 448.f) return s | 0x7E;
    if (a < 0.015625f) {                       // subnormal: step 2^-9
        int q = (int)(a * 512.0f + 0.5f);
        return s | (unsigned char)q;
    }
    unsigned int u = __float_as_uint(a);
    u += 0x0007FFFF + ((u >> 20) & 1);         // RNE to 3 mantissa bits (carry-safe)
    int e8 = (int)((u >> 23) & 0xFF) - 120;    // -127+7
    if (e8 >= 16) return s | 0x7E;
    return s | (unsigned char)((e8 << 3) | ((u >> 20) & 7));
}
__device__ __forceinline__ void gload_lds16(const void* g, void* l) {
    // async global->LDS, 16B/lane; LDS dest = wave-uniform base + lane*16 (linear!)
    __builtin_amdgcn_global_load_lds((const __attribute__((address_space(1))) void*)g,
                                     (__attribute__((address_space(3))) void*)l, 16, 0, 0);
}

// ---------- constants ----------
#define BATCH 256
#define CHAN  768
#define HW    196
#define SPS   196
#define HID   512
#define MROWS 50176   // BATCH*SPS
#define K1    1536    // 2*CHAN
#define WSCL  64.0f           // weights pre-scaled by 64 (e4m3 subnormal dodge)
#define WINV  0.015625f       // 1/64 applied after each GEMM
#define SC1   0x7F7F7F7F      // E8M0 scale 1.0 in every byte

// Fused MLP R21: BM=128 (halves per-row B L2-traffic vs R20's BM=64 — that delivery
// was the measured critical path: 1290 cyc/tile vs 1100 cyc MFMA) AND spill-free
// (R20's proven constraint: per-wave live <= 128 regs).  Both at once via 16 waves:
// 1024 threads, phase-1 4M x 4N, per-wave 32 rows x 128 cols -> acc[2][8] = 64 regs,
// live ~100 <= 128.  4 waves/SIMD TLP hides the dbuf drain (R17's intent, without
// its spill).  LDS 160KB, 1 blk/CU: [A0 16K | A1 16K | B0 64K | B1 64K].
// Phase 2 barrier-free: wave owns 32 cols, b2f[2][4] (64 regs, loaded after acc
// dies) from L2-hot W2t; h1l (64KB) over dead B0; red[128][33] over dead A0/A1.
// Ledger: kt=11 reads A1/B1 -> B0 and A0/A1 are dead at their reuse points.

// ---------- weight prep: in [K][N] fp32 -> out [N][K] fp8 of (w * 64) ----------
__global__ void transpose_cast_fp8(const float* __restrict__ in, unsigned char* __restrict__ out,
                                   int K, int N) {
    int idx = blockIdx.x * 256 + threadIdx.x;
    if (idx >= K * N) return;
    int n = idx / K, k = idx - n * K;
    out[idx] = f2fp8(in[(size_t)k * N + n] * WSCL);
}

// ---------- gather: feats fp8 via HW cvt_pk, 4B packed stores; deltaxy out ----------
__global__ __launch_bounds__(256) void gather_feats(const float* __restrict__ x,
                                                    const int* __restrict__ pxs,
                                                    const int* __restrict__ pys,
                                                    unsigned char* __restrict__ feats,
                                                    float* __restrict__ out) {
    __shared__ float lds[64 * 197];   // pitch 197: conflict-free
    int chunk = blockIdx.x;           // 0..11 (64-channel chunk)
    int b     = blockIdx.y;           // 0..255
    int c0 = chunk * 64;
    const float* xb = x + ((size_t)b * CHAN + c0) * HW;
    for (int t = threadIdx.x; t < 64 * HW; t += 256) {
        int j = t / HW, p = t - j * HW;
        lds[j * 197 + p] = xb[t];     // coalesced read of 64 full channels
    }
    if (chunk == 0) {                 // per-batch: deltaxy (pred written by fused kernel)
        for (int i = threadIdx.x; i < SPS * 2; i += 256) {
            int idx = b * SPS * 2 + i;
            out[MROWS * 2 + idx] = (float)(pxs[idx] - pys[idx]) + 13.0f;  // (H-1)=13
        }
    }
    __syncthreads();
    int wid = threadIdx.x >> 6, lane = threadIdx.x & 63;
    int g = lane >> 4;                // s-offset within the 4-s pack
    int cq = (lane & 15) * 4;         // channel quad
    for (int sb = wid * 4; sb < SPS; sb += 16) {
        int s = sb + g;
        int base = (b * SPS + s) * 2;
        int ix = pxs[base] * 14 + pxs[base + 1];
        int iy = pys[base] * 14 + pys[base + 1];
        const float* lx = lds + cq * 197;
        unsigned int ux = 0, uy = 0;
        ux = __builtin_amdgcn_cvt_pk_fp8_f32(lx[ix],       lx[197 + ix], ux, false);
        ux = __builtin_amdgcn_cvt_pk_fp8_f32(lx[394 + ix], lx[591 + ix], ux, true);
        uy = __builtin_amdgcn_cvt_pk_fp8_f32(lx[iy],       lx[197 + iy], uy, false);
        uy = __builtin_amdgcn_cvt_pk_fp8_f32(lx[394 + iy], lx[591 + iy], uy, true);
        size_t ro = (size_t)(b * SPS + s) * K1;
        *(unsigned int*)(feats + ro + c0 + cq)        = ux;
        *(unsigned int*)(feats + ro + CHAN + c0 + cq) = uy;
    }
}

// ---------- fused MLP: pred = relu(relu(feats@W1+b1)@W2+b2)@W3 + b3 ----------
__global__ __launch_bounds__(1024, 1)
void mlp_fused(const unsigned char* __restrict__ feats,
               const unsigned char* __restrict__ W1t,
               const float* __restrict__ b1,
               const unsigned char* __restrict__ W2t,
               const float* __restrict__ b2,
               const float* __restrict__ W3,
               const float* __restrict__ b3,
               float* __restrict__ out) {
    extern __shared__ char smem[];    // 163840 B
    const int t = threadIdx.x;
    const int wid = t >> 6, lane = t & 63;
    const int wr = wid >> 2, wcn = wid & 3;   // phase 1: 4M x 4N, wave owns 32 x 128
    const int lr = lane & 15, lk = lane >> 4;
    const int mBase = blockIdx.x * 128;
    f32x4 acc[2][8] = {};             // 64 regs -> live ~100 <= 128-reg budget: no spill

    // ---- Phase 1: GEMM1, 12 K-tiles, full dbuf, issue-early ----
    auto stage1 = [&](int buf, int kt) {
        char* Ab = smem + buf * 16384;
        char* Bb = smem + 32768 + buf * 65536;
        {                                         // A: 1024 units = 128 rows x 128B
            int row = t >> 3, cs = (t & 7) ^ (row & 7);
            gload_lds16(feats + (size_t)(mBase + row) * K1 + kt * 128 + cs * 16,
                        Ab + t * 16);
        }
        #pragma unroll
        for (int i = 0; i < 4; ++i) {             // B: 4096 units = 512 rows x 128B
            int lin = i * 1024 + t, row = lin >> 3, cs = (lin & 7) ^ (row & 7);
            gload_lds16(W1t + (size_t)row * K1 + kt * 128 + cs * 16,
                        Bb + lin * 16);
        }
    };
    auto frag128 = [&](const char* rowp, int r) -> int8v {   // swizzled 32B frag, 128B row
        union { int4v h[2]; int8v v; } u;
        u.h[0] = *(const int4v*)(rowp + (((2 * lk + 0) ^ (r & 7)) * 16));
        u.h[1] = *(const int4v*)(rowp + (((2 * lk + 1) ^ (r & 7)) * 16));
        return u.v;
    };
    auto compute1 = [&](int buf) {
        const char* Ab = smem + buf * 16384;
        const char* Bb = smem + 32768 + buf * 65536;
        int8v af[2];
        #pragma unroll
        for (int m = 0; m < 2; ++m) {
            int r = wr * 32 + m * 16 + lr;
            af[m] = frag128(Ab + r * 128, r);
        }
        #pragma unroll
        for (int n = 0; n < 8; ++n) {             // one B frag live at a time
            int r = wcn * 128 + n * 16 + lr;
            int8v bf = frag128(Bb + r * 128, r);
            #pragma unroll
            for (int m = 0; m < 2; ++m)
                acc[m][n] = __builtin_amdgcn_mfma_scale_f32_16x16x128_f8f6f4(
                    af[m], bf, acc[m][n], 0, 0, 0, SC1, 0, SC1);
        }
    };

    stage1(0, 0);
    __syncthreads();
    int cur = 0;
    for (int kt = 0; kt < 12; ++kt) {
        if (kt + 1 < 12) stage1(cur ^ 1, kt + 1);   // flies under compute(kt)
        compute1(cur);
        __syncthreads();
        cur ^= 1;
    }
    // ledger: kt=11 read buf1 (A1/B1) -> B0 (h1l) and A0/A1 (red) are dead.

    // ---- handoff: h1 = relu(acc/64 + b1) -> LDS fp8 [128 rows][512B], swizzled ----
    char* h1l = smem + 32768;         // 64KB over dead B0; slot = chunk^(r&31)
    float* red = (float*)smem;        // [128][33] f32 = 16.9KB over dead A0/A1
    #pragma unroll
    for (int n = 0; n < 8; ++n) {
        int c = wcn * 128 + n * 16 + lr;
        int c16 = wcn * 8 + n;        // c>>4 (lr<16)
        float bv = b1[c];
        #pragma unroll
        for (int m = 0; m < 2; ++m) {
            int r0 = wr * 32 + m * 16 + lk * 4;
            float v0 = fmaxf(acc[m][n][0] * WINV + bv, 0.f);
            float v1 = fmaxf(acc[m][n][1] * WINV + bv, 0.f);
            float v2 = fmaxf(acc[m][n][2] * WINV + bv, 0.f);
            float v3 = fmaxf(acc[m][n][3] * WINV + bv, 0.f);
            unsigned int u = __builtin_amdgcn_cvt_pk_fp8_f32(v0, v1, 0u, false);
            u = __builtin_amdgcn_cvt_pk_fp8_f32(v2, v3, u, true);
            #pragma unroll
            for (int j = 0; j < 4; ++j) {
                int r = r0 + j;
                h1l[r * 512 + ((c16 ^ (r & 31)) * 16) + lr] =
                    (unsigned char)((u >> (8 * j)) & 0xff);
            }
        }
    }
    __syncthreads();                  // h1 visible; acc dead past here

    // ---- Phase 2 preload: wave wid owns cols [32*wid, +32); 8 B2 frags from L2 ----
    int8v b2f[2][4];                  // 64 regs (acc freed)
    float bv2[2], w30[2], w31[2];
    #pragma unroll
    for (int n2 = 0; n2 < 2; ++n2) {
        int c2 = wid * 32 + n2 * 16 + lr;
        const unsigned char* rp = W2t + (size_t)c2 * 512;
        #pragma unroll
        for (int kt2 = 0; kt2 < 4; ++kt2)
            b2f[n2][kt2] = *(const int8v*)(rp + kt2 * 128 + lk * 32);   // 32B aligned, L2-hot
        bv2[n2] = b2[c2];
        w30[n2] = W3[c2 * 2];
        w31[n2] = W3[c2 * 2 + 1];
    }

    // ---- Phase 2: barrier-free; 8 strips x (2 n2 x 4 kt2) MFMA; pred folded ----
    auto frag512 = [&](int r, int kt2) -> int8v {   // swizzled h1 read, 512B row
        int g = kt2 * 8 + lk * 2;
        union { int4v h[2]; int8v v; } u;
        u.h[0] = *(const int4v*)(h1l + r * 512 + (((g + 0) ^ (r & 31)) * 16));
        u.h[1] = *(const int4v*)(h1l + r * 512 + (((g + 1) ^ (r & 31)) * 16));
        return u.v;
    };
    #pragma unroll
    for (int s = 0; s < 8; ++s) {
        f32x4 acc2[2] = {};
        #pragma unroll
        for (int kt2 = 0; kt2 < 4; ++kt2) {
            int8v a2 = frag512(s * 16 + lr, kt2);
            acc2[0] = __builtin_amdgcn_mfma_scale_f32_16x16x128_f8f6f4(
                a2, b2f[0][kt2], acc2[0], 0, 0, 0, SC1, 0, SC1);
            acc2[1] = __builtin_amdgcn_mfma_scale_f32_16x16x128_f8f6f4(
                a2, b2f[1][kt2], acc2[1], 0, 0, 0, SC1, 0, SC1);
        }
        float p0[4] = {0.f, 0.f, 0.f, 0.f}, p1[4] = {0.f, 0.f, 0.f, 0.f};
        #pragma unroll
        for (int n2 = 0; n2 < 2; ++n2) {
            #pragma unroll
            for (int j = 0; j < 4; ++j) {
                float v = fmaxf(acc2[n2][j] * WINV + bv2[n2], 0.f);
                p0[j] += v * w30[n2];
                p1[j] += v * w31[n2];
            }
        }
        #pragma unroll
        for (int j = 0; j < 4; ++j) {
            #pragma unroll
            for (int msk = 1; msk < 16; msk <<= 1) {   // reduce over the 16 lr-lanes (cols)
                p0[j] += __shfl_xor(p0[j], msk);
                p1[j] += __shfl_xor(p1[j], msk);
            }
            if (lr == 0) {
                int r = s * 16 + lk * 4 + j;           // C-layout: row = lk*4+j
                red[r * 33 + wid * 2 + 0] = p0[j];     // pad-33 stride: conflict-free
                red[r * 33 + wid * 2 + 1] = p1[j];
            }
        }
    }
    __syncthreads();

    // ---- final: sum 16 wave-partials per (row, comp); direct store ----
    if (t < 256) {
        int row = t >> 1, comp = t & 1;
        float v = b3[comp];
        #pragma unroll
        for (int w = 0; w < 16; ++w)
            v += red[row * 33 + w * 2 + comp];
        out[(size_t)(mBase + row) * 2 + comp] = v;
    }
}

// ---------- launch ----------
extern "C" void kernel_launch(void* const* d_in, const int* in_sizes, int n_in,
                              void* d_out, int out_size, void* d_ws, size_t ws_size,
                              hipStream_t stream) {
    const float* x  = (const float*)d_in[0];
    const float* W1 = (const float*)d_in[1];
    const float* b1 = (const float*)d_in[2];
    const float* W2 = (const float*)d_in[3];
    const float* b2 = (const float*)d_in[4];
    const float* W3 = (const float*)d_in[5];
    const float* b3 = (const float*)d_in[6];
    const int*  pxs = (const int*)d_in[7];
    const int*  pys = (const int*)d_in[8];
    float* out = (float*)d_out;
    char* ws = (char*)d_ws;

    // ws layout (bytes): W1t 786,432 | W2t 262,144 | feats 77,070,336
    unsigned char* W1t   = (unsigned char*)(ws + 0);
    unsigned char* W2t   = (unsigned char*)(ws + 786432);
    unsigned char* feats = (unsigned char*)(ws + 1048576);   // end 78,118,912

    hipFuncSetAttribute((const void*)mlp_fused,
                        hipFuncAttributeMaxDynamicSharedMemorySize, 163840);

    transpose_cast_fp8<<<(K1 * HID + 255) / 256, 256, 0, stream>>>(W1, W1t, K1, HID);
    transpose_cast_fp8<<<(HID * HID + 255) / 256, 256, 0, stream>>>(W2, W2t, HID, HID);
    gather_feats<<<dim3(12, BATCH), 256, 0, stream>>>(x, pxs, pys, feats, out);
    // fused MLP: grid = 392 blocks x 128 rows, 1024 threads (16 waves), 160KB LDS
    mlp_fused<<<MROWS / 128, 1024, 163840, stream>>>(feats, W1t, b1, W2t, b2, W3, b3, out);
}

// Round 22
// 164.837 us; speedup vs baseline: 1.4195x; 1.4195x over previous
//
#include <hip/hip_runtime.h>
#include <hip/hip_bf16.h>

// ---------- types / helpers ----------
typedef __attribute__((ext_vector_type(4))) float f32x4;   // MFMA C/D frag
typedef __attribute__((ext_vector_type(4))) int   int4v;   // one 16B load
typedef __attribute__((ext_vector_type(8))) int   int8v;   // K=128 fp8 A/B frag (32B)

// float -> OCP e4m3fn byte (cold path: weight prep only)
__device__ __forceinline__ unsigned char f2fp8(float f) {
    unsigned char s = (__float_as_uint(f) >> 24) & 0x80;
    float a = fabsf(f);
    if (a >= 448.f) return s | 0x7E;
    if (a < 0.015625f) {                       // subnormal: step 2^-9
        int q = (int)(a * 512.0f + 0.5f);
        return s | (unsigned char)q;
    }
    unsigned int u = __float_as_uint(a);
    u += 0x0007FFFF + ((u >> 20) & 1);         // RNE to 3 mantissa bits (carry-safe)
    int e8 = (int)((u >> 23) & 0xFF) - 120;    // -127+7
    if (e8 >= 16) return s | 0x7E;
    return s | (unsigned char)((e8 << 3) | ((u >> 20) & 7));
}
__device__ __forceinline__ void gload_lds16(const void* g, void* l) {
    // async global->LDS, 16B/lane; LDS dest = wave-uniform base + lane*16 (linear!)
    __builtin_amdgcn_global_load_lds((const __attribute__((address_space(1))) void*)g,
                                     (__attribute__((address_space(3))) void*)l, 16, 0, 0);
}

// ---------- constants ----------
#define BATCH 256
#define CHAN  768
#define HW    196
#define SPS   196
#define HID   512
#define MROWS 50176   // BATCH*SPS
#define K1    1536    // 2*CHAN
#define WSCL  64.0f           // weights pre-scaled by 64 (e4m3 subnormal dodge)
#define WINV  0.015625f       // 1/64 applied after each GEMM
#define SC1   0x7F7F7F7F      // E8M0 scale 1.0 in every byte

// R22: back to UNFUSED, with every GEMM 2-blocks/CU AND spill-free (the two
// session-proven constraints, satisfied together for the first time):
//   - R11 evidence: 2 blk/CU runs ~1.6 us/block-tile vs ~3.9 serial at 1 blk/CU.
//   - R17/R21 evidence: 1024 thr -> 64-reg budget -> spill; 512 thr -> 128 budget.
// Geometry: BM=64, BN=256, BK=128; 512 thr = 8 waves 1M x 8N (wave = 64 rows x
// 32 cols, acc[4][2]=32 regs; live ~90 <= 128).  LDS = [A0 8K|A1 8K|B0 32K|B1 32K]
// = 80KB -> exactly 2 blocks/CU (160KB pool).  Issue-early dbuf, 1 sync/tile.
// GEMM1: h1 = relu(feats@W1t/64+b1) -> fp8 global.  GEMM2 (predMode): pred =
// relu(h1@W2t/64+b2)@W3 via LDS-reduce + atomicAdd (2 contenders; out pred rows
// initialized to b3 by gather each call — R8-proven pattern).

// ---------- weight prep: in [K][N] fp32 -> out [N][K] fp8 of (w * 64) ----------
__global__ void transpose_cast_fp8(const float* __restrict__ in, unsigned char* __restrict__ out,
                                   int K, int N) {
    int idx = blockIdx.x * 256 + threadIdx.x;
    if (idx >= K * N) return;
    int n = idx / K, k = idx - n * K;
    out[idx] = f2fp8(in[(size_t)k * N + n] * WSCL);
}

// ---------- gather + out-init: feats fp8 via HW cvt_pk; pred=b3; deltaxy ----------
__global__ __launch_bounds__(256) void gather_feats(const float* __restrict__ x,
                                                    const int* __restrict__ pxs,
                                                    const int* __restrict__ pys,
                                                    const float* __restrict__ b3,
                                                    unsigned char* __restrict__ feats,
                                                    float* __restrict__ out) {
    __shared__ float lds[64 * 197];   // pitch 197: conflict-free
    int chunk = blockIdx.x;           // 0..11 (64-channel chunk)
    int b     = blockIdx.y;           // 0..255
    int c0 = chunk * 64;
    const float* xb = x + ((size_t)b * CHAN + c0) * HW;
    for (int t = threadIdx.x; t < 64 * HW; t += 256) {
        int j = t / HW, p = t - j * HW;
        lds[j * 197 + p] = xb[t];     // coalesced read of 64 full channels
    }
    if (chunk == 0) {                 // per-batch: pred rows = b3 (GEMM2 atomics add), deltaxy
        float b30 = b3[0], b31 = b3[1];
        for (int i = threadIdx.x; i < SPS * 2; i += 256) {
            int idx = b * SPS * 2 + i;
            out[idx] = (i & 1) ? b31 : b30;
            out[MROWS * 2 + idx] = (float)(pxs[idx] - pys[idx]) + 13.0f;  // (H-1)=13
        }
    }
    __syncthreads();
    int wid = threadIdx.x >> 6, lane = threadIdx.x & 63;
    int g = lane >> 4;                // s-offset within the 4-s pack
    int cq = (lane & 15) * 4;         // channel quad
    for (int sb = wid * 4; sb < SPS; sb += 16) {
        int s = sb + g;
        int base = (b * SPS + s) * 2;
        int ix = pxs[base] * 14 + pxs[base + 1];
        int iy = pys[base] * 14 + pys[base + 1];
        const float* lx = lds + cq * 197;
        unsigned int ux = 0, uy = 0;
        ux = __builtin_amdgcn_cvt_pk_fp8_f32(lx[ix],       lx[197 + ix], ux, false);
        ux = __builtin_amdgcn_cvt_pk_fp8_f32(lx[394 + ix], lx[591 + ix], ux, true);
        uy = __builtin_amdgcn_cvt_pk_fp8_f32(lx[iy],       lx[197 + iy], uy, false);
        uy = __builtin_amdgcn_cvt_pk_fp8_f32(lx[394 + iy], lx[591 + iy], uy, true);
        size_t ro = (size_t)(b * SPS + s) * K1;
        *(unsigned int*)(feats + ro + c0 + cq)        = ux;
        *(unsigned int*)(feats + ro + CHAN + c0 + cq) = uy;
    }
}

// ---------- 64x256 MX-fp8 GEMM, 2 blocks/CU, spill-free ----------
// C = relu((A @ Bt^T)/64 + bias) -> fp8 (predMode=0), or pred-fold (predMode=1).
// Grid 1-D: nHalf = bid&1 (cols 0-255 / 256-511), mChunk = bid>>1.
__global__ __launch_bounds__(512, 2)
void gemm64(const unsigned char* __restrict__ A,
            const unsigned char* __restrict__ Bt,
            const float* __restrict__ bias,
            unsigned char* __restrict__ C,
            const float* __restrict__ W3,
            float* __restrict__ out,
            int Kd, int predMode) {
    extern __shared__ char smem[];    // 81920 B: [A0 8K | A1 8K | B0 32K | B1 32K]
    const int t = threadIdx.x;
    const int wid = t >> 6, lane = t & 63;
    const int lr = lane & 15, lk = lane >> 4;
    const int mBase = (blockIdx.x >> 1) * 64;
    const int nBase = (blockIdx.x & 1) * 256;
    const int nK = Kd >> 7;           // BK=128
    f32x4 acc[4][2] = {};             // 32 regs; live ~90 <= 128-reg budget: no spill

    auto stage = [&](int buf, int kt) {
        char* Ab = smem + buf * 8192;
        char* Bb = smem + 16384 + buf * 32768;
        {                                         // A: 512 units = 64 rows x 128B
            int row = t >> 3, cs = (t & 7) ^ (row & 7);
            gload_lds16(A + (size_t)(mBase + row) * Kd + kt * 128 + cs * 16,
                        Ab + t * 16);
        }
        #pragma unroll
        for (int i = 0; i < 4; ++i) {             // B: 2048 units = 256 rows x 128B
            int lin = i * 512 + t, row = lin >> 3, cs = (lin & 7) ^ (row & 7);
            gload_lds16(Bt + (size_t)(nBase + row) * Kd + kt * 128 + cs * 16,
                        Bb + lin * 16);
        }
    };
    auto frag128 = [&](const char* rowp, int r) -> int8v {   // swizzled 32B frag, 128B row
        union { int4v h[2]; int8v v; } u;
        u.h[0] = *(const int4v*)(rowp + (((2 * lk + 0) ^ (r & 7)) * 16));
        u.h[1] = *(const int4v*)(rowp + (((2 * lk + 1) ^ (r & 7)) * 16));
        return u.v;
    };
    auto compute = [&](int buf) {
        const char* Ab = smem + buf * 8192;
        const char* Bb = smem + 16384 + buf * 32768;
        int8v af[4];
        #pragma unroll
        for (int m = 0; m < 4; ++m) {             // all waves share rows 0..63 (broadcast)
            int r = m * 16 + lr;
            af[m] = frag128(Ab + r * 128, r);
        }
        #pragma unroll
        for (int n = 0; n < 2; ++n) {             // one B frag live at a time
            int r = wid * 32 + n * 16 + lr;
            int8v bf = frag128(Bb + r * 128, r);
            #pragma unroll
            for (int m = 0; m < 4; ++m)
                acc[m][n] = __builtin_amdgcn_mfma_scale_f32_16x16x128_f8f6f4(
                    af[m], bf, acc[m][n], 0, 0, 0, SC1, 0, SC1);
        }
    };

    stage(0, 0);
    __syncthreads();
    int cur = 0;
    for (int kt = 0; kt < nK; ++kt) {
        if (kt + 1 < nK) stage(cur ^ 1, kt + 1);   // flies under compute(kt)
        compute(cur);
        __syncthreads();
        cur ^= 1;
    }

    if (!predMode) {
        // h1 = relu(acc/64 + b1) -> fp8 global.  C row=lk*4+j, col=lane&15 (verified)
        #pragma unroll
        for (int n = 0; n < 2; ++n) {
            int c = nBase + wid * 32 + n * 16 + lr;
            float bv = bias[c];
            #pragma unroll
            for (int m = 0; m < 4; ++m) {
                int r0 = mBase + m * 16 + lk * 4;
                float v0 = fmaxf(acc[m][n][0] * WINV + bv, 0.f);
                float v1 = fmaxf(acc[m][n][1] * WINV + bv, 0.f);
                float v2 = fmaxf(acc[m][n][2] * WINV + bv, 0.f);
                float v3 = fmaxf(acc[m][n][3] * WINV + bv, 0.f);
                unsigned int u = __builtin_amdgcn_cvt_pk_fp8_f32(v0, v1, 0u, false);
                u = __builtin_amdgcn_cvt_pk_fp8_f32(v2, v3, u, true);
                #pragma unroll
                for (int j = 0; j < 4; ++j)
                    C[(size_t)(r0 + j) * HID + c] = (unsigned char)((u >> (8 * j)) & 0xff);
            }
        }
    } else {
        // pred fold: pred[r] += sum_c relu(acc/64+b2)[r][c] * W3[c][:]
        float* red = (float*)smem;    // [64][17] f32 = 4.4KB over dead A0/A1
        float bv2[2], w30[2], w31[2];
        #pragma unroll
        for (int n = 0; n < 2; ++n) {
            int c = nBase + wid * 32 + n * 16 + lr;
            bv2[n] = bias[c];
            w30[n] = W3[c * 2];
            w31[n] = W3[c * 2 + 1];
        }
        __syncthreads();              // all LDS reads of A/B done before red overwrite
        #pragma unroll
        for (int m = 0; m < 4; ++m) {
            #pragma unroll
            for (int j = 0; j < 4; ++j) {
                float p0 = 0.f, p1 = 0.f;
                #pragma unroll
                for (int n = 0; n < 2; ++n) {
                    float v = fmaxf(acc[m][n][j] * WINV + bv2[n], 0.f);
                    p0 += v * w30[n];
                    p1 += v * w31[n];
                }
                #pragma unroll
                for (int msk = 1; msk < 16; msk <<= 1) {   // reduce over 16 lr-lanes
                    p0 += __shfl_xor(p0, msk);
                    p1 += __shfl_xor(p1, msk);
                }
                if (lr == 0) {
                    int rl = m * 16 + lk * 4 + j;          // 0..63
                    red[rl * 17 + wid * 2 + 0] = p0;
                    red[rl * 17 + wid * 2 + 1] = p1;
                }
            }
        }
        __syncthreads();
        if (t < 128) {   // one (row, comp) per thread; 8-way sum; ONE atomic each
            int rl = t >> 1, comp = t & 1;
            float v = 0.f;
            #pragma unroll
            for (int w = 0; w < 8; ++w)
                v += red[rl * 17 + w * 2 + comp];
            atomicAdd(&out[(size_t)(mBase + rl) * 2 + comp], v);   // 2 contenders
        }
    }
}

// ---------- launch ----------
extern "C" void kernel_launch(void* const* d_in, const int* in_sizes, int n_in,
                              void* d_out, int out_size, void* d_ws, size_t ws_size,
                              hipStream_t stream) {
    const float* x  = (const float*)d_in[0];
    const float* W1 = (const float*)d_in[1];
    const float* b1 = (const float*)d_in[2];
    const float* W2 = (const float*)d_in[3];
    const float* b2 = (const float*)d_in[4];
    const float* W3 = (const float*)d_in[5];
    const float* b3 = (const float*)d_in[6];
    const int*  pxs = (const int*)d_in[7];
    const int*  pys = (const int*)d_in[8];
    float* out = (float*)d_out;
    char* ws = (char*)d_ws;

    // ws layout (bytes): W1t 786,432 | W2t 262,144 | h1 25,690,112 | feats 77,070,336
    unsigned char* W1t   = (unsigned char*)(ws + 0);
    unsigned char* W2t   = (unsigned char*)(ws + 786432);
    unsigned char* h1    = (unsigned char*)(ws + 1048576);
    unsigned char* feats = (unsigned char*)(ws + 26738688);   // end 103,809,024

    hipFuncSetAttribute((const void*)gemm64,
                        hipFuncAttributeMaxDynamicSharedMemorySize, 81920);

    transpose_cast_fp8<<<(K1 * HID + 255) / 256, 256, 0, stream>>>(W1, W1t, K1, HID);
    transpose_cast_fp8<<<(HID * HID + 255) / 256, 256, 0, stream>>>(W2, W2t, HID, HID);
    // gather inits out (pred=b3, deltaxy) and writes feats
    gather_feats<<<dim3(12, BATCH), 256, 0, stream>>>(x, pxs, pys, b3, feats, out);
    // GEMM1: h1 = relu(feats @ W1t^T /64 + b1)   grid = 784 mChunks x 2 nHalves
    gemm64<<<(MROWS / 64) * 2, 512, 81920, stream>>>(
        feats, W1t, b1, h1, nullptr, nullptr, K1, 0);
    // GEMM2 (+GEMM3 fold): out[0:2M) += relu(h1 @ W2t^T /64 + b2) @ W3
    gemm64<<<(MROWS / 64) * 2, 512, 81920, stream>>>(
        h1, W2t, b2, nullptr, W3, out, HID, 1);
}

// Round 23
// 159.088 us; speedup vs baseline: 1.4708x; 1.0361x over previous
//
#include <hip/hip_runtime.h>
#include <hip/hip_bf16.h>

// ---------- types / helpers ----------
typedef __attribute__((ext_vector_type(4))) float f32x4;   // MFMA C/D frag
typedef __attribute__((ext_vector_type(4))) int   int4v;   // one 16B load
typedef __attribute__((ext_vector_type(8))) int   int8v;   // K=128 fp8 A/B frag (32B)

// float -> OCP e4m3fn byte (cold path: weight prep only)
__device__ __forceinline__ unsigned char f2fp8(float f) {
    unsigned char s = (__float_as_uint(f) >> 24) & 0x80;
    float a = fabsf(f);
    if (a >= 448.f) return s | 0x7E;
    if (a < 0.015625f) {                       // subnormal: step 2^-9
        int q = (int)(a * 512.0f + 0.5f);
        return s | (unsigned char)q;
    }
    unsigned int u = __float_as_uint(a);
    u += 0x0007FFFF + ((u >> 20) & 1);         // RNE to 3 mantissa bits (carry-safe)
    int e8 = (int)((u >> 23) & 0xFF) - 120;    // -127+7
    if (e8 >= 16) return s | 0x7E;
    return s | (unsigned char)((e8 << 3) | ((u >> 20) & 7));
}
__device__ __forceinline__ void gload_lds16(const void* g, void* l) {
    // async global->LDS, 16B/lane; LDS dest = wave-uniform base + lane*16 (linear!)
    __builtin_amdgcn_global_load_lds((const __attribute__((address_space(1))) void*)g,
                                     (__attribute__((address_space(3))) void*)l, 16, 0, 0);
}

// ---------- constants ----------
#define BATCH 256
#define CHAN  768
#define HW    196
#define SPS   196
#define HID   512
#define MROWS 50176   // BATCH*SPS
#define K1    1536    // 2*CHAN
#define WSCL  64.0f           // weights pre-scaled by 64 (e4m3 subnormal dodge)
#define WINV  0.015625f       // 1/64 applied after each GEMM
#define SC1   0x7F7F7F7F      // E8M0 scale 1.0 in every byte
#define GPITCH 198            // gather LDS row pitch (floats): 8B-aligned rows (float2
                              // stores), scatter-read banks (792q+ix)%32 worst 4-way

// ---------- weight prep: in [K][N] fp32 -> out [N][K] fp8 of (w * 64) ----------
__global__ void transpose_cast_fp8(const float* __restrict__ in, unsigned char* __restrict__ out,
                                   int K, int N) {
    int idx = blockIdx.x * 256 + threadIdx.x;
    if (idx >= K * N) return;
    int n = idx / K, k = idx - n * K;
    out[idx] = f2fp8(in[(size_t)k * N + n] * WSCL);
}

// ---------- gather + out-init (R23: 512 thr -> 24 waves/CU; float4 staging) ----------
// R22 profile: gather 97us, HBM 20%, VALU 16%, Occ 29% -> latency-bound at 12 waves/CU
// with 49 scalar loads/thread.  Fix: 8 waves/block (3 blk/CU = 24 waves) + float4
// staging (rows = exactly 49 float4; 4x fewer load instrs) + int2 index loads.
__global__ __launch_bounds__(512) void gather_feats(const float* __restrict__ x,
                                                    const int* __restrict__ pxs,
                                                    const int* __restrict__ pys,
                                                    const float* __restrict__ b3,
                                                    unsigned char* __restrict__ feats,
                                                    float* __restrict__ out) {
    __shared__ float lds[64 * GPITCH];   // 50,688 B -> 3 blocks/CU
    int chunk = blockIdx.x;           // 0..11 (64-channel chunk)
    int b     = blockIdx.y;           // 0..255
    int c0 = chunk * 64;
    const float4* xb4 = (const float4*)(x + ((size_t)b * CHAN + c0) * HW);  // 16B-aligned
    for (int vt = threadIdx.x; vt < 64 * 49; vt += 512) {    // 64 rows x 49 float4
        float4 v = xb4[vt];
        int j = vt / 49, p4 = vt - j * 49;
        float* dst = &lds[j * GPITCH + p4 * 4];              // 8B-aligned (GPITCH even)
        *(float2*)(dst + 0) = make_float2(v.x, v.y);
        *(float2*)(dst + 2) = make_float2(v.z, v.w);
    }
    if (chunk == 0) {                 // per-batch: pred rows = b3 (GEMM2 atomics add), deltaxy
        float b30 = b3[0], b31 = b3[1];
        for (int i = threadIdx.x; i < SPS * 2; i += 512) {
            int idx = b * SPS * 2 + i;
            out[idx] = (i & 1) ? b31 : b30;
            out[MROWS * 2 + idx] = (float)(pxs[idx] - pys[idx]) + 13.0f;  // (H-1)=13
        }
    }
    __syncthreads();
    int wid = threadIdx.x >> 6, lane = threadIdx.x & 63;
    int g = lane >> 4;                // s-offset within the 4-s pack
    int cq = (lane & 15) * 4;         // channel quad
    const float* lx = lds + cq * GPITCH;
    // s = 4*wid + 32k + g covers 0..195 exactly once (4w+g spans 0..31 mod 32)
    for (int sb = wid * 4; sb < SPS; sb += 32) {
        int s = sb + g;
        int base = (b * SPS + s) * 2;
        int2 vx = *(const int2*)(pxs + base);    // 8B-aligned (even index)
        int2 vy = *(const int2*)(pys + base);
        int ix = vx.x * 14 + vx.y;
        int iy = vy.x * 14 + vy.y;
        unsigned int ux = 0, uy = 0;
        ux = __builtin_amdgcn_cvt_pk_fp8_f32(lx[ix],              lx[GPITCH + ix],     ux, false);
        ux = __builtin_amdgcn_cvt_pk_fp8_f32(lx[2 * GPITCH + ix], lx[3 * GPITCH + ix], ux, true);
        uy = __builtin_amdgcn_cvt_pk_fp8_f32(lx[iy],              lx[GPITCH + iy],     uy, false);
        uy = __builtin_amdgcn_cvt_pk_fp8_f32(lx[2 * GPITCH + iy], lx[3 * GPITCH + iy], uy, true);
        size_t ro = (size_t)(b * SPS + s) * K1;
        *(unsigned int*)(feats + ro + c0 + cq)        = ux;   // 64B coalesced per 16-lane group
        *(unsigned int*)(feats + ro + CHAN + c0 + cq) = uy;
    }
}

// ---------- 64x256 MX-fp8 GEMM, 2 blocks/CU, spill-free (R22, proven) ----------
// C = relu((A @ Bt^T)/64 + bias) -> fp8 (predMode=0), or pred-fold (predMode=1).
// Grid 1-D: nHalf = bid&1 (cols 0-255 / 256-511), mChunk = bid>>1.
__global__ __launch_bounds__(512, 2)
void gemm64(const unsigned char* __restrict__ A,
            const unsigned char* __restrict__ Bt,
            const float* __restrict__ bias,
            unsigned char* __restrict__ C,
            const float* __restrict__ W3,
            float* __restrict__ out,
            int Kd, int predMode) {
    extern __shared__ char smem[];    // 81920 B: [A0 8K | A1 8K | B0 32K | B1 32K]
    const int t = threadIdx.x;
    const int wid = t >> 6, lane = t & 63;
    const int lr = lane & 15, lk = lane >> 4;
    const int mBase = (blockIdx.x >> 1) * 64;
    const int nBase = (blockIdx.x & 1) * 256;
    const int nK = Kd >> 7;           // BK=128
    f32x4 acc[4][2] = {};             // 32 regs; live ~90 <= 128-reg budget: no spill

    auto stage = [&](int buf, int kt) {
        char* Ab = smem + buf * 8192;
        char* Bb = smem + 16384 + buf * 32768;
        {                                         // A: 512 units = 64 rows x 128B
            int row = t >> 3, cs = (t & 7) ^ (row & 7);
            gload_lds16(A + (size_t)(mBase + row) * Kd + kt * 128 + cs * 16,
                        Ab + t * 16);
        }
        #pragma unroll
        for (int i = 0; i < 4; ++i) {             // B: 2048 units = 256 rows x 128B
            int lin = i * 512 + t, row = lin >> 3, cs = (lin & 7) ^ (row & 7);
            gload_lds16(Bt + (size_t)(nBase + row) * Kd + kt * 128 + cs * 16,
                        Bb + lin * 16);
        }
    };
    auto frag128 = [&](const char* rowp, int r) -> int8v {   // swizzled 32B frag, 128B row
        union { int4v h[2]; int8v v; } u;
        u.h[0] = *(const int4v*)(rowp + (((2 * lk + 0) ^ (r & 7)) * 16));
        u.h[1] = *(const int4v*)(rowp + (((2 * lk + 1) ^ (r & 7)) * 16));
        return u.v;
    };
    auto compute = [&](int buf) {
        const char* Ab = smem + buf * 8192;
        const char* Bb = smem + 16384 + buf * 32768;
        int8v af[4];
        #pragma unroll
        for (int m = 0; m < 4; ++m) {             // all waves share rows 0..63 (broadcast)
            int r = m * 16 + lr;
            af[m] = frag128(Ab + r * 128, r);
        }
        #pragma unroll
        for (int n = 0; n < 2; ++n) {             // one B frag live at a time
            int r = wid * 32 + n * 16 + lr;
            int8v bf = frag128(Bb + r * 128, r);
            #pragma unroll
            for (int m = 0; m < 4; ++m)
                acc[m][n] = __builtin_amdgcn_mfma_scale_f32_16x16x128_f8f6f4(
                    af[m], bf, acc[m][n], 0, 0, 0, SC1, 0, SC1);
        }
    };

    stage(0, 0);
    __syncthreads();
    int cur = 0;
    for (int kt = 0; kt < nK; ++kt) {
        if (kt + 1 < nK) stage(cur ^ 1, kt + 1);   // flies under compute(kt)
        compute(cur);
        __syncthreads();
        cur ^= 1;
    }

    if (!predMode) {
        // h1 = relu(acc/64 + b1) -> fp8 global.  C row=lk*4+j, col=lane&15 (verified)
        #pragma unroll
        for (int n = 0; n < 2; ++n) {
            int c = nBase + wid * 32 + n * 16 + lr;
            float bv = bias[c];
            #pragma unroll
            for (int m = 0; m < 4; ++m) {
                int r0 = mBase + m * 16 + lk * 4;
                float v0 = fmaxf(acc[m][n][0] * WINV + bv, 0.f);
                float v1 = fmaxf(acc[m][n][1] * WINV + bv, 0.f);
                float v2 = fmaxf(acc[m][n][2] * WINV + bv, 0.f);
                float v3 = fmaxf(acc[m][n][3] * WINV + bv, 0.f);
                unsigned int u = __builtin_amdgcn_cvt_pk_fp8_f32(v0, v1, 0u, false);
                u = __builtin_amdgcn_cvt_pk_fp8_f32(v2, v3, u, true);
                #pragma unroll
                for (int j = 0; j < 4; ++j)
                    C[(size_t)(r0 + j) * HID + c] = (unsigned char)((u >> (8 * j)) & 0xff);
            }
        }
    } else {
        // pred fold: pred[r] += sum_c relu(acc/64+b2)[r][c] * W3[c][:]
        float* red = (float*)smem;    // [64][17] f32 = 4.4KB over dead A0/A1
        float bv2[2], w30[2], w31[2];
        #pragma unroll
        for (int n = 0; n < 2; ++n) {
            int c = nBase + wid * 32 + n * 16 + lr;
            bv2[n] = bias[c];
            w30[n] = W3[c * 2];
            w31[n] = W3[c * 2 + 1];
        }
        __syncthreads();              // all LDS reads of A/B done before red overwrite
        #pragma unroll
        for (int m = 0; m < 4; ++m) {
            #pragma unroll
            for (int j = 0; j < 4; ++j) {
                float p0 = 0.f, p1 = 0.f;
                #pragma unroll
                for (int n = 0; n < 2; ++n) {
                    float v = fmaxf(acc[m][n][j] * WINV + bv2[n], 0.f);
                    p0 += v * w30[n];
                    p1 += v * w31[n];
                }
                #pragma unroll
                for (int msk = 1; msk < 16; msk <<= 1) {   // reduce over 16 lr-lanes
                    p0 += __shfl_xor(p0, msk);
                    p1 += __shfl_xor(p1, msk);
                }
                if (lr == 0) {
                    int rl = m * 16 + lk * 4 + j;          // 0..63
                    red[rl * 17 + wid * 2 + 0] = p0;
                    red[rl * 17 + wid * 2 + 1] = p1;
                }
            }
        }
        __syncthreads();
        if (t < 128) {   // one (row, comp) per thread; 8-way sum; ONE atomic each
            int rl = t >> 1, comp = t & 1;
            float v = 0.f;
            #pragma unroll
            for (int w = 0; w < 8; ++w)
                v += red[rl * 17 + w * 2 + comp];
            atomicAdd(&out[(size_t)(mBase + rl) * 2 + comp], v);   // 2 contenders
        }
    }
}

// ---------- launch ----------
extern "C" void kernel_launch(void* const* d_in, const int* in_sizes, int n_in,
                              void* d_out, int out_size, void* d_ws, size_t ws_size,
                              hipStream_t stream) {
    const float* x  = (const float*)d_in[0];
    const float* W1 = (const float*)d_in[1];
    const float* b1 = (const float*)d_in[2];
    const float* W2 = (const float*)d_in[3];
    const float* b2 = (const float*)d_in[4];
    const float* W3 = (const float*)d_in[5];
    const float* b3 = (const float*)d_in[6];
    const int*  pxs = (const int*)d_in[7];
    const int*  pys = (const int*)d_in[8];
    float* out = (float*)d_out;
    char* ws = (char*)d_ws;

    // ws layout (bytes): W1t 786,432 | W2t 262,144 | h1 25,690,112 | feats 77,070,336
    unsigned char* W1t   = (unsigned char*)(ws + 0);
    unsigned char* W2t   = (unsigned char*)(ws + 786432);
    unsigned char* h1    = (unsigned char*)(ws + 1048576);
    unsigned char* feats = (unsigned char*)(ws + 26738688);   // end 103,809,024

    hipFuncSetAttribute((const void*)gemm64,
                        hipFuncAttributeMaxDynamicSharedMemorySize, 81920);

    transpose_cast_fp8<<<(K1 * HID + 255) / 256, 256, 0, stream>>>(W1, W1t, K1, HID);
    transpose_cast_fp8<<<(HID * HID + 255) / 256, 256, 0, stream>>>(W2, W2t, HID, HID);
    // gather inits out (pred=b3, deltaxy) and writes feats; 512 thr -> 24 waves/CU
    gather_feats<<<dim3(12, BATCH), 512, 0, stream>>>(x, pxs, pys, b3, feats, out);
    // GEMM1: h1 = relu(feats @ W1t^T /64 + b1)   grid = 784 mChunks x 2 nHalves
    gemm64<<<(MROWS / 64) * 2, 512, 81920, stream>>>(
        feats, W1t, b1, h1, nullptr, nullptr, K1, 0);
    // GEMM2 (+GEMM3 fold): out[0:2M) += relu(h1 @ W2t^T /64 + b2) @ W3
    gemm64<<<(MROWS / 64) * 2, 512, 81920, stream>>>(
        h1, W2t, b2, nullptr, W3, out, HID, 1);
}

// Round 24
// 145.654 us; speedup vs baseline: 1.6065x; 1.0922x over previous
//
#include <hip/hip_runtime.h>
#include <hip/hip_bf16.h>

// ---------- types / helpers ----------
typedef __attribute__((ext_vector_type(4))) float f32x4;   // MFMA C/D frag
typedef __attribute__((ext_vector_type(4))) int   int4v;   // one 16B load
typedef __attribute__((ext_vector_type(8))) int   int8v;   // K=128 fp8 A/B frag (32B)

// float -> OCP e4m3fn byte (cold path: weight prep only)
__device__ __forceinline__ unsigned char f2fp8(float f) {
    unsigned char s = (__float_as_uint(f) >> 24) & 0x80;
    float a = fabsf(f);
    if (a >= 448.f) return s | 0x7E;
    if (a < 0.015625f) {                       // subnormal: step 2^-9
        int q = (int)(a * 512.0f + 0.5f);
        return s | (unsigned char)q;
    }
    unsigned int u = __float_as_uint(a);
    u += 0x0007FFFF + ((u >> 20) & 1);         // RNE to 3 mantissa bits (carry-safe)
    int e8 = (int)((u >> 23) & 0xFF) - 120;    // -127+7
    if (e8 >= 16) return s | 0x7E;
    return s | (unsigned char)((e8 << 3) | ((u >> 20) & 7));
}
__device__ __forceinline__ void gload_lds16(const void* g, void* l) {
    // async global->LDS, 16B/lane; LDS dest = wave-uniform base + lane*16 (linear!)
    // global SOURCE is per-lane -> gathered (indexed-row) staging is legal.
    __builtin_amdgcn_global_load_lds((const __attribute__((address_space(1))) void*)g,
                                     (__attribute__((address_space(3))) void*)l, 16, 0, 0);
}

// ---------- constants ----------
#define BATCH 256
#define CHAN  768
#define HW    196
#define SPS   196
#define HID   512
#define MROWS 50176   // BATCH*SPS
#define K1    1536    // 2*CHAN
#define WSCL  64.0f           // weights pre-scaled by 64 (e4m3 subnormal dodge)
#define WINV  0.015625f       // 1/64 applied after each GEMM
#define SC1   0x7F7F7F7F      // E8M0 scale 1.0 in every byte
#define GPITCH 198            // xpose8 LDS row pitch (floats)

// R24: gather-free GEMM1.  feats (77MB write + 77MB read) is never materialized.
// xpose8 builds x8[b][pos][c] fp8 (38.5MB) + pidx (gathered row ids); GEMM1 stages
// its A tiles STRAIGHT from x8 using per-row gathered source addresses
// (global_load_lds source is per-lane).  A feats row [kt*128,+128) == x8 row
// pidx[r*2 + (kt>=6)] bytes [(kt%6)*128,+128) -- contiguous, swizzle unchanged.

// ---------- weight prep: in [K][N] fp32 -> out [N][K] fp8 of (w * 64) ----------
__global__ void transpose_cast_fp8(const float* __restrict__ in, unsigned char* __restrict__ out,
                                   int K, int N) {
    int idx = blockIdx.x * 256 + threadIdx.x;
    if (idx >= K * N) return;
    int n = idx / K, k = idx - n * K;
    out[idx] = f2fp8(in[(size_t)k * N + n] * WSCL);
}

// ---------- xpose8: x[b][c][pos] fp32 -> x8[b][pos][c] fp8; pidx; out-init ----------
__global__ __launch_bounds__(512) void xpose8(const float* __restrict__ x,
                                              const int* __restrict__ pxs,
                                              const int* __restrict__ pys,
                                              const float* __restrict__ b3,
                                              unsigned char* __restrict__ x8,
                                              int* __restrict__ pidx,
                                              float* __restrict__ out) {
    __shared__ float lds[64 * GPITCH];   // 50,688 B -> 3 blocks/CU
    int chunk = blockIdx.x;           // 0..11 (64-channel chunk)
    int b     = blockIdx.y;           // 0..255
    int c0 = chunk * 64;
    const float4* xb4 = (const float4*)(x + ((size_t)b * CHAN + c0) * HW);  // 16B-aligned
    for (int vt = threadIdx.x; vt < 64 * 49; vt += 512) {    // 64 rows x 49 float4
        float4 v = xb4[vt];
        int j = vt / 49, p4 = vt - j * 49;
        float* dst = &lds[j * GPITCH + p4 * 4];              // 8B-aligned (GPITCH even)
        *(float2*)(dst + 0) = make_float2(v.x, v.y);
        *(float2*)(dst + 2) = make_float2(v.z, v.w);
    }
    if (chunk == 0) {                 // per-batch: pred=b3, deltaxy, pidx
        float b30 = b3[0], b31 = b3[1];
        for (int i = threadIdx.x; i < SPS * 2; i += 512) {
            int idx = b * SPS * 2 + i;
            out[idx] = (i & 1) ? b31 : b30;
            out[MROWS * 2 + idx] = (float)(pxs[idx] - pys[idx]) + 13.0f;  // (H-1)=13
        }
        for (int s = threadIdx.x; s < SPS; s += 512) {
            int base = (b * SPS + s) * 2;
            int ix = pxs[base] * 14 + pxs[base + 1];
            int iy = pys[base] * 14 + pys[base + 1];
            pidx[(b * SPS + s) * 2 + 0] = b * HW + ix;
            pidx[(b * SPS + s) * 2 + 1] = b * HW + iy;
        }
    }
    __syncthreads();
    int wid = threadIdx.x >> 6, lane = threadIdx.x & 63;
    int g = lane >> 4;                // pos-offset within the 4-pos pack
    int cq = (lane & 15) * 4;         // channel quad
    const float* lx = lds + cq * GPITCH;
    // p = 4*wid + 32k + g covers 0..195 exactly once
    for (int pb = wid * 4; pb < HW; pb += 32) {
        int p = pb + g;
        unsigned int u = 0;
        u = __builtin_amdgcn_cvt_pk_fp8_f32(lx[p],              lx[GPITCH + p],     u, false);
        u = __builtin_amdgcn_cvt_pk_fp8_f32(lx[2 * GPITCH + p], lx[3 * GPITCH + p], u, true);
        *(unsigned int*)(x8 + ((size_t)b * HW + p) * CHAN + c0 + cq) = u;  // 64B/16-lane grp
    }
}

// ---------- 64x256 MX-fp8 GEMM, 2 blocks/CU, spill-free; optional gathered-A ----------
// C = relu((A @ Bt^T)/64 + bias) -> fp8 (predMode=0), or pred-fold (predMode=1).
// pidx != nullptr: A rows are gathered from x8 (row pidx[r*2+(kt>=6)], 768B rows).
// Grid 1-D: nHalf = bid&1 (cols 0-255 / 256-511), mChunk = bid>>1.
__global__ __launch_bounds__(512, 2)
void gemm64(const unsigned char* __restrict__ A,
            const unsigned char* __restrict__ Bt,
            const float* __restrict__ bias,
            unsigned char* __restrict__ C,
            const float* __restrict__ W3,
            float* __restrict__ out,
            const int* __restrict__ pidx,
            int Kd, int predMode) {
    extern __shared__ char smem[];    // 81920 B: [A0 8K | A1 8K | B0 32K | B1 32K]
    const int t = threadIdx.x;
    const int wid = t >> 6, lane = t & 63;
    const int lr = lane & 15, lk = lane >> 4;
    const int mBase = (blockIdx.x >> 1) * 64;
    const int nBase = (blockIdx.x & 1) * 256;
    const int nK = Kd >> 7;           // BK=128
    f32x4 acc[4][2] = {};             // 32 regs; live ~90 <= 128-reg budget: no spill

    // gathered-A row ids for this thread's fixed staging row (t>>3), L2-hot
    int prx = 0, pry = 0;
    if (pidx) {
        int gr = mBase + (t >> 3);
        prx = pidx[gr * 2 + 0];
        pry = pidx[gr * 2 + 1];
    }

    auto stage = [&](int buf, int kt) {
        char* Ab = smem + buf * 8192;
        char* Bb = smem + 16384 + buf * 32768;
        {                                         // A: 512 units = 64 rows x 128B
            int row = t >> 3, cs = (t & 7) ^ (row & 7);
            const unsigned char* asrc;
            if (pidx) {                           // gathered from x8 (768B rows)
                int srcRow = (kt < 6) ? prx : pry;
                int kk = (kt < 6) ? kt : kt - 6;
                asrc = A + (size_t)srcRow * CHAN + kk * 128 + cs * 16;
            } else {
                asrc = A + (size_t)(mBase + row) * Kd + kt * 128 + cs * 16;
            }
            gload_lds16(asrc, Ab + t * 16);
        }
        #pragma unroll
        for (int i = 0; i < 4; ++i) {             // B: 2048 units = 256 rows x 128B
            int lin = i * 512 + t, row = lin >> 3, cs = (lin & 7) ^ (row & 7);
            gload_lds16(Bt + (size_t)(nBase + row) * Kd + kt * 128 + cs * 16,
                        Bb + lin * 16);
        }
    };
    auto frag128 = [&](const char* rowp, int r) -> int8v {   // swizzled 32B frag, 128B row
        union { int4v h[2]; int8v v; } u;
        u.h[0] = *(const int4v*)(rowp + (((2 * lk + 0) ^ (r & 7)) * 16));
        u.h[1] = *(const int4v*)(rowp + (((2 * lk + 1) ^ (r & 7)) * 16));
        return u.v;
    };
    auto compute = [&](int buf) {
        const char* Ab = smem + buf * 8192;
        const char* Bb = smem + 16384 + buf * 32768;
        int8v af[4];
        #pragma unroll
        for (int m = 0; m < 4; ++m) {             // all waves share rows 0..63 (broadcast)
            int r = m * 16 + lr;
            af[m] = frag128(Ab + r * 128, r);
        }
        #pragma unroll
        for (int n = 0; n < 2; ++n) {             // one B frag live at a time
            int r = wid * 32 + n * 16 + lr;
            int8v bf = frag128(Bb + r * 128, r);
            #pragma unroll
            for (int m = 0; m < 4; ++m)
                acc[m][n] = __builtin_amdgcn_mfma_scale_f32_16x16x128_f8f6f4(
                    af[m], bf, acc[m][n], 0, 0, 0, SC1, 0, SC1);
        }
    };

    stage(0, 0);
    __syncthreads();
    int cur = 0;
    for (int kt = 0; kt < nK; ++kt) {
        if (kt + 1 < nK) stage(cur ^ 1, kt + 1);   // flies under compute(kt)
        compute(cur);
        __syncthreads();
        cur ^= 1;
    }

    if (!predMode) {
        // h1 = relu(acc/64 + b1) -> fp8 global.  C row=lk*4+j, col=lane&15 (verified)
        #pragma unroll
        for (int n = 0; n < 2; ++n) {
            int c = nBase + wid * 32 + n * 16 + lr;
            float bv = bias[c];
            #pragma unroll
            for (int m = 0; m < 4; ++m) {
                int r0 = mBase + m * 16 + lk * 4;
                float v0 = fmaxf(acc[m][n][0] * WINV + bv, 0.f);
                float v1 = fmaxf(acc[m][n][1] * WINV + bv, 0.f);
                float v2 = fmaxf(acc[m][n][2] * WINV + bv, 0.f);
                float v3 = fmaxf(acc[m][n][3] * WINV + bv, 0.f);
                unsigned int u = __builtin_amdgcn_cvt_pk_fp8_f32(v0, v1, 0u, false);
                u = __builtin_amdgcn_cvt_pk_fp8_f32(v2, v3, u, true);
                #pragma unroll
                for (int j = 0; j < 4; ++j)
                    C[(size_t)(r0 + j) * HID + c] = (unsigned char)((u >> (8 * j)) & 0xff);
            }
        }
    } else {
        // pred fold: pred[r] += sum_c relu(acc/64+b2)[r][c] * W3[c][:]
        float* red = (float*)smem;    // [64][17] f32 = 4.4KB over dead A0/A1
        float bv2[2], w30[2], w31[2];
        #pragma unroll
        for (int n = 0; n < 2; ++n) {
            int c = nBase + wid * 32 + n * 16 + lr;
            bv2[n] = bias[c];
            w30[n] = W3[c * 2];
            w31[n] = W3[c * 2 + 1];
        }
        __syncthreads();              // all LDS reads of A/B done before red overwrite
        #pragma unroll
        for (int m = 0; m < 4; ++m) {
            #pragma unroll
            for (int j = 0; j < 4; ++j) {
                float p0 = 0.f, p1 = 0.f;
                #pragma unroll
                for (int n = 0; n < 2; ++n) {
                    float v = fmaxf(acc[m][n][j] * WINV + bv2[n], 0.f);
                    p0 += v * w30[n];
                    p1 += v * w31[n];
                }
                #pragma unroll
                for (int msk = 1; msk < 16; msk <<= 1) {   // reduce over 16 lr-lanes
                    p0 += __shfl_xor(p0, msk);
                    p1 += __shfl_xor(p1, msk);
                }
                if (lr == 0) {
                    int rl = m * 16 + lk * 4 + j;          // 0..63
                    red[rl * 17 + wid * 2 + 0] = p0;
                    red[rl * 17 + wid * 2 + 1] = p1;
                }
            }
        }
        __syncthreads();
        if (t < 128) {   // one (row, comp) per thread; 8-way sum; ONE atomic each
            int rl = t >> 1, comp = t & 1;
            float v = 0.f;
            #pragma unroll
            for (int w = 0; w < 8; ++w)
                v += red[rl * 17 + w * 2 + comp];
            atomicAdd(&out[(size_t)(mBase + rl) * 2 + comp], v);   // 2 contenders
        }
    }
}

// ---------- launch ----------
extern "C" void kernel_launch(void* const* d_in, const int* in_sizes, int n_in,
                              void* d_out, int out_size, void* d_ws, size_t ws_size,
                              hipStream_t stream) {
    const float* x  = (const float*)d_in[0];
    const float* W1 = (const float*)d_in[1];
    const float* b1 = (const float*)d_in[2];
    const float* W2 = (const float*)d_in[3];
    const float* b2 = (const float*)d_in[4];
    const float* W3 = (const float*)d_in[5];
    const float* b3 = (const float*)d_in[6];
    const int*  pxs = (const int*)d_in[7];
    const int*  pys = (const int*)d_in[8];
    float* out = (float*)d_out;
    char* ws = (char*)d_ws;

    // ws layout (bytes): W1t 786,432 | W2t 262,144 | h1 25,690,112 |
    //                    x8 38,535,168 | pidx 401,408  (end 65,675,264)
    unsigned char* W1t  = (unsigned char*)(ws + 0);
    unsigned char* W2t  = (unsigned char*)(ws + 786432);
    unsigned char* h1   = (unsigned char*)(ws + 1048576);
    unsigned char* x8   = (unsigned char*)(ws + 26738688);
    int*           pidx = (int*)(ws + 65273856);

    hipFuncSetAttribute((const void*)gemm64,
                        hipFuncAttributeMaxDynamicSharedMemorySize, 81920);

    transpose_cast_fp8<<<(K1 * HID + 255) / 256, 256, 0, stream>>>(W1, W1t, K1, HID);
    transpose_cast_fp8<<<(HID * HID + 255) / 256, 256, 0, stream>>>(W2, W2t, HID, HID);
    // xpose8: x8 + pidx + out-init (pred=b3, deltaxy)
    xpose8<<<dim3(12, BATCH), 512, 0, stream>>>(x, pxs, pys, b3, x8, pidx, out);
    // GEMM1 (gathered A): h1 = relu(gather(x8)@W1t^T /64 + b1)
    gemm64<<<(MROWS / 64) * 2, 512, 81920, stream>>>(
        x8, W1t, b1, h1, nullptr, nullptr, pidx, K1, 0);
    // GEMM2 (+GEMM3 fold): out[0:2M) += relu(h1 @ W2t^T /64 + b2) @ W3
    gemm64<<<(MROWS / 64) * 2, 512, 81920, stream>>>(
        h1, W2t, b2, nullptr, W3, out, nullptr, HID, 1);
}